// Round 1
// baseline (1365.190 us; speedup 1.0000x reference)
//
#include <hip/hip_runtime.h>

#define DIM 1024
#define NKN 65536
#define TOK 4096
#define CK 20
#define FK 10
#define RNK 128
#define CAP 128

typedef __bf16 v8bf __attribute__((ext_vector_type(8)));
typedef float v4f __attribute__((ext_vector_type(4)));
typedef unsigned short u16x8 __attribute__((ext_vector_type(8)));

__device__ __forceinline__ unsigned short f2bf(float f) {
  // round-to-nearest-even fp32 -> bf16 (finite inputs only)
  unsigned u = __builtin_bit_cast(unsigned, f);
  u += 0x7FFFu + ((u >> 16) & 1u);
  return (unsigned short)(u >> 16);
}

// ---------------------------------------------------------------------------
// K1: transpose W_router [DIM][NKN] -> WT fp32 [NKN][DIM] and WT bf16 [NKN][DIM]
// ---------------------------------------------------------------------------
__global__ __launch_bounds__(256) void k_transpose(const float* __restrict__ W,
                                                   float* __restrict__ WT,
                                                   unsigned short* __restrict__ WTb) {
  __shared__ float tile[32][33];
  const int n0 = (blockIdx.x & 2047) << 5;
  const int d0 = (blockIdx.x >> 11) << 5;
  const int c = threadIdx.x & 31, r0 = threadIdx.x >> 5;
#pragma unroll
  for (int i = 0; i < 4; i++) {
    int r = r0 + i * 8;
    tile[r][c] = W[(size_t)(d0 + r) * NKN + n0 + c];
  }
  __syncthreads();
#pragma unroll
  for (int i = 0; i < 4; i++) {
    int r = r0 + i * 8;
    float v = tile[c][r];  // = W[d0+c][n0+r]
    size_t o = (size_t)(n0 + r) * DIM + d0 + c;
    WT[o] = v;
    WTb[o] = f2bf(v);
  }
}

// ---------------------------------------------------------------------------
// K1b: convert x fp32 -> bf16
// ---------------------------------------------------------------------------
__global__ __launch_bounds__(256) void k_cvt_x(const float* __restrict__ x,
                                               unsigned short* __restrict__ xb) {
  const int i = blockIdx.x * 256 + threadIdx.x;  // 1M threads, 4 elems each
  const float4 v = reinterpret_cast<const float4*>(x)[i];
  ushort4 o;
  o.x = f2bf(v.x); o.y = f2bf(v.y); o.z = f2bf(v.z); o.w = f2bf(v.w);
  reinterpret_cast<ushort4*>(xb)[i] = o;
}

// ---------------------------------------------------------------------------
// K2: bf16 MFMA GEMM  logits[m][n] = sum_k A[m][k] * Bt[n][k], store bf16
// 128x128 tile, BK=32, 4 waves (2x2), 16x16x32 MFMA, global_load_lds staging
// ---------------------------------------------------------------------------
__global__ __launch_bounds__(256) void k_gemm(const unsigned short* __restrict__ A,
                                              const unsigned short* __restrict__ Bt,
                                              unsigned short* __restrict__ Lg) {
  __shared__ __align__(16) unsigned short As[128 * 32];
  __shared__ __align__(16) unsigned short Bs[128 * 32];
  const int tid = threadIdx.x;
  const int lane = tid & 63, wid = tid >> 6;
  const int mb = blockIdx.x & 31, nb = blockIdx.x >> 5;  // m-fast: B tile reused by 32 consecutive blocks
  const int m0 = mb << 7, n0 = nb << 7;
  const int wm = wid >> 1, wn = wid & 1;
  v4f acc[4][4] = {};

  // staging: tile = 4096 bf16 elems; 2 issues of (256 threads x 8 elems)
  const int e0 = tid * 8;
  const int row0 = e0 >> 5, k0 = e0 & 31;
  const int e1 = 2048 + e0;
  const int row1 = e1 >> 5, k1 = e1 & 31;
  const unsigned short* a0 = A + (size_t)(m0 + row0) * DIM + k0;
  const unsigned short* a1 = A + (size_t)(m0 + row1) * DIM + k1;
  const unsigned short* b0 = Bt + (size_t)(n0 + row0) * DIM + k0;
  const unsigned short* b1 = Bt + (size_t)(n0 + row1) * DIM + k1;
  unsigned short* lA0 = &As[wid * 512];          // wave-uniform LDS bases
  unsigned short* lA1 = &As[2048 + wid * 512];
  unsigned short* lB0 = &Bs[wid * 512];
  unsigned short* lB1 = &Bs[2048 + wid * 512];

  const int rm = lane & 15, kk = (lane >> 4) * 8;

  for (int kt = 0; kt < DIM; kt += 32) {
    __syncthreads();
    __builtin_amdgcn_global_load_lds((const __attribute__((address_space(1))) void*)(a0 + kt),
                                     (__attribute__((address_space(3))) void*)lA0, 16, 0, 0);
    __builtin_amdgcn_global_load_lds((const __attribute__((address_space(1))) void*)(a1 + kt),
                                     (__attribute__((address_space(3))) void*)lA1, 16, 0, 0);
    __builtin_amdgcn_global_load_lds((const __attribute__((address_space(1))) void*)(b0 + kt),
                                     (__attribute__((address_space(3))) void*)lB0, 16, 0, 0);
    __builtin_amdgcn_global_load_lds((const __attribute__((address_space(1))) void*)(b1 + kt),
                                     (__attribute__((address_space(3))) void*)lB1, 16, 0, 0);
    __syncthreads();

    v8bf af[4], bfr[4];
#pragma unroll
    for (int i = 0; i < 4; i++)
      af[i] = *reinterpret_cast<const v8bf*>(&As[(wm * 64 + i * 16 + rm) * 32 + kk]);
#pragma unroll
    for (int i = 0; i < 4; i++)
      bfr[i] = *reinterpret_cast<const v8bf*>(&Bs[(wn * 64 + i * 16 + rm) * 32 + kk]);
#pragma unroll
    for (int i = 0; i < 4; i++)
#pragma unroll
      for (int j = 0; j < 4; j++)
        acc[i][j] = __builtin_amdgcn_mfma_f32_16x16x32_bf16(af[i], bfr[j], acc[i][j], 0, 0, 0);
  }

  // C/D layout (verified m89/m91): n = lane&15, m = (lane>>4)*4 + reg
  const int mr = (lane >> 4) * 4;
#pragma unroll
  for (int i = 0; i < 4; i++) {
#pragma unroll
    for (int j = 0; j < 4; j++) {
      const int mrow = m0 + wm * 64 + i * 16 + mr;
      const int ncol = n0 + wn * 64 + j * 16 + rm;
#pragma unroll
      for (int r = 0; r < 4; r++)
        Lg[(size_t)(mrow + r) * NKN + ncol] = f2bf(acc[i][j][r]);
    }
  }
}

// ---------------------------------------------------------------------------
// K3: per-token candidate selection via 4096-bucket histogram on bf16 keys
// collects all elements in buckets >= threshold bucket (>=32 guaranteed)
// ---------------------------------------------------------------------------
__global__ __launch_bounds__(256) void k_select(const unsigned short* __restrict__ Lg,
                                                int* __restrict__ cidx,
                                                int* __restrict__ ccnt) {
  __shared__ int hist[4096];
  __shared__ int psum[256];
  __shared__ int bstar, scnt;
  const int t = blockIdx.x, tid = threadIdx.x;
  const u16x8* row = reinterpret_cast<const u16x8*>(Lg + (size_t)t * NKN);
  for (int i = tid; i < 4096; i += 256) hist[i] = 0;
  if (tid == 0) scnt = 0;
  __syncthreads();
  for (int i = tid; i < NKN / 8; i += 256) {
    u16x8 v = row[i];
#pragma unroll
    for (int j = 0; j < 8; j++) {
      unsigned short b = v[j];
      unsigned short key = (b & 0x8000) ? (unsigned short)(~b) : (unsigned short)(b | 0x8000);
      atomicAdd(&hist[key >> 4], 1);
    }
  }
  __syncthreads();
  int s = 0;
#pragma unroll
  for (int b = 0; b < 16; b++) s += hist[tid * 16 + b];
  psum[tid] = s;
  __syncthreads();
  if (tid == 0) {
    int cum = 0, g = 255;
    for (; g >= 0; g--) {
      if (cum + psum[g] >= 32) break;
      cum += psum[g];
    }
    int bsel = 0;
    if (g >= 0) {
      int b = g * 16 + 15;
      for (;; b--) {
        cum += hist[b];
        if (cum >= 32 || b == g * 16) break;
      }
      bsel = b;
    }
    bstar = bsel;
  }
  __syncthreads();
  const int bs = bstar;
  for (int i = tid; i < NKN / 8; i += 256) {
    u16x8 v = row[i];
#pragma unroll
    for (int j = 0; j < 8; j++) {
      unsigned short b = v[j];
      unsigned short key = (b & 0x8000) ? (unsigned short)(~b) : (unsigned short)(b | 0x8000);
      if ((int)(key >> 4) >= bs) {
        int p = atomicAdd(&scnt, 1);
        if (p < CAP) cidx[(size_t)t * CAP + p] = i * 8 + j;
      }
    }
  }
  __syncthreads();
  if (tid == 0) ccnt[t] = min(scnt, CAP);
}

// ---------------------------------------------------------------------------
// K4: exact fp64 rescore of candidates + exact top-20 selection
// ---------------------------------------------------------------------------
__global__ __launch_bounds__(256) void k_rescore(const float* __restrict__ x,
                                                 const float* __restrict__ WT,
                                                 const int* __restrict__ cidx,
                                                 const int* __restrict__ ccnt,
                                                 int* __restrict__ coarse) {
  __shared__ float xs[DIM];
  __shared__ double sc[CAP];
  __shared__ int ci[CAP];
  const int t = blockIdx.x, tid = threadIdx.x;
  const int lane = tid & 63, w = tid >> 6;
  const int cnt = ccnt[t];
  for (int i = tid; i < DIM; i += 256) xs[i] = x[(size_t)t * DIM + i];
  for (int i = tid; i < CAP; i += 256) {
    sc[i] = -1e300;
    ci[i] = (i < cnt) ? cidx[(size_t)t * CAP + i] : 0;
  }
  __syncthreads();
  for (int c = w; c < cnt; c += 4) {
    const float* wr = WT + (size_t)ci[c] * DIM;
    double sacc = 0.0;
#pragma unroll 4
    for (int i = lane; i < DIM; i += 64) sacc += (double)xs[i] * (double)wr[i];
#pragma unroll
    for (int off = 32; off > 0; off >>= 1) sacc += __shfl_down(sacc, off);
    if (lane == 0) sc[c] = sacc;
  }
  __syncthreads();
  if (w == 0) {
    double va = sc[lane], vb = sc[lane + 64];
    int ia = lane, ib = lane + 64;
    for (int kk = 0; kk < CK; kk++) {
      double v1 = va; int i1 = ia;
      if (vb > v1) { v1 = vb; i1 = ib; }
#pragma unroll
      for (int off = 32; off > 0; off >>= 1) {
        double ov = __shfl_down(v1, off);
        int oi = __shfl_down(i1, off);
        if (ov > v1) { v1 = ov; i1 = oi; }
      }
      i1 = __shfl(i1, 0);
      if (lane == 0) coarse[(size_t)t * CK + kk] = ci[i1];
      if (i1 == ia) va = -1e300;
      if (i1 == ib) vb = -1e300;
    }
  }
}

// ---------------------------------------------------------------------------
// K5: query = x @ W_enc   (4 tokens per block, 128 threads = one output col each)
// ---------------------------------------------------------------------------
__global__ __launch_bounds__(128) void k_query(const float* __restrict__ x,
                                               const float* __restrict__ Wenc,
                                               float* __restrict__ q) {
  const int j = threadIdx.x;
  const int t0 = blockIdx.x * 4;
  float s0 = 0.f, s1 = 0.f, s2 = 0.f, s3 = 0.f;
  const float* x0 = x + (size_t)t0 * DIM;
  for (int d = 0; d < DIM; d++) {
    float wv = Wenc[d * RNK + j];
    s0 = fmaf(x0[d], wv, s0);
    s1 = fmaf(x0[DIM + d], wv, s1);
    s2 = fmaf(x0[2 * DIM + d], wv, s2);
    s3 = fmaf(x0[3 * DIM + d], wv, s3);
  }
  q[(size_t)t0 * RNK + j] = s0;
  q[(size_t)(t0 + 1) * RNK + j] = s1;
  q[(size_t)(t0 + 2) * RNK + j] = s2;
  q[(size_t)(t0 + 3) * RNK + j] = s3;
}

// ---------------------------------------------------------------------------
// K6: fine scores vs 20 candidates, top-10, softmax, weighted V blend
// ---------------------------------------------------------------------------
__global__ __launch_bounds__(256) void k_fine(const float* __restrict__ q,
                                              const float* __restrict__ Kall,
                                              const float* __restrict__ Vall,
                                              const int* __restrict__ coarse,
                                              float* __restrict__ out) {
  __shared__ float qs[RNK];
  __shared__ float fsc[CK];
  __shared__ int gix[CK];
  __shared__ float wts[FK];
  __shared__ int fidx[FK];
  const int t = blockIdx.x, tid = threadIdx.x;
  const int lane = tid & 63, w = tid >> 6;
  if (tid < RNK) qs[tid] = q[(size_t)t * RNK + tid];
  if (tid < CK) gix[tid] = coarse[(size_t)t * CK + tid];
  __syncthreads();
  for (int c = w; c < CK; c += 4) {
    const float* kr = Kall + (size_t)gix[c] * RNK;
    float s = 0.f;
    s = fmaf(qs[lane], kr[lane], s);
    s = fmaf(qs[lane + 64], kr[lane + 64], s);
#pragma unroll
    for (int off = 32; off > 0; off >>= 1) s += __shfl_down(s, off);
    if (lane == 0) fsc[c] = s * 0.08838834764831843f;  // 1/sqrt(128)
  }
  __syncthreads();
  if (w == 0) {
    float vv = (lane < CK) ? fsc[lane] : -3e38f;
    float myv = -3e38f; int myp = 0;
    for (int kk = 0; kk < FK; kk++) {
      float v1 = vv; int p1 = lane;
#pragma unroll
      for (int off = 32; off > 0; off >>= 1) {
        float ov = __shfl_down(v1, off);
        int op = __shfl_down(p1, off);
        if (ov > v1) { v1 = ov; p1 = op; }
      }
      v1 = __shfl(v1, 0); p1 = __shfl(p1, 0);
      if (lane == kk) { myv = v1; myp = p1; }
      if (lane == p1) vv = -3e38f;
    }
    float sv = (lane < FK) ? myv : -3e38f;
    float mx = sv;
#pragma unroll
    for (int off = 8; off > 0; off >>= 1) mx = fmaxf(mx, __shfl_xor(mx, off, 16));
    float e = (lane < FK) ? expf(sv - mx) : 0.f;
    float se = e;
#pragma unroll
    for (int off = 8; off > 0; off >>= 1) se += __shfl_xor(se, off, 16);
    if (lane < FK) { wts[lane] = e / se; fidx[lane] = gix[myp]; }
  }
  __syncthreads();
  float4 a = make_float4(0.f, 0.f, 0.f, 0.f);
#pragma unroll
  for (int f = 0; f < FK; f++) {
    const float wt = wts[f];
    const float4 v = *reinterpret_cast<const float4*>(&Vall[(size_t)fidx[f] * DIM + tid * 4]);
    a.x = fmaf(wt, v.x, a.x);
    a.y = fmaf(wt, v.y, a.y);
    a.z = fmaf(wt, v.z, a.z);
    a.w = fmaf(wt, v.w, a.w);
  }
  *reinterpret_cast<float4*>(&out[(size_t)t * DIM + tid * 4]) = a;
}

// ---------------------------------------------------------------------------

extern "C" void kernel_launch(void* const* d_in, const int* in_sizes, int n_in,
                              void* d_out, int out_size, void* d_ws, size_t ws_size,
                              hipStream_t stream) {
  const float* x = (const float*)d_in[0];      // [2,2048,1024] = [4096][1024]
  const float* Wr = (const float*)d_in[1];     // [1024][65536]
  const float* Wenc = (const float*)d_in[2];   // [1024][128]
  const float* Kall = (const float*)d_in[3];   // [65536][128]
  const float* Vall = (const float*)d_in[4];   // [65536][1024]
  float* out = (float*)d_out;                  // [4096][1024]

  char* ws = (char*)d_ws;
  constexpr size_t OFF_WT = 0;                  // fp32 W^T   256 MB
  constexpr size_t OFF_WTB = 268435456;         // bf16 W^T   128 MB
  constexpr size_t OFF_XB = 402653184;          // bf16 x       8 MB
  constexpr size_t OFF_LG = 411041792;          // bf16 logits 512 MB
  constexpr size_t OFF_Q = 947912704;           // fp32 query   2 MB
  constexpr size_t OFF_CIDX = 950009856;        // int cand     2 MB
  constexpr size_t OFF_CCNT = 952107008;        // int cnt     16 KB
  constexpr size_t OFF_COARSE = 952123392;      // int top20  320 KB
  float* WT = (float*)(ws + OFF_WT);
  unsigned short* WTb = (unsigned short*)(ws + OFF_WTB);
  unsigned short* xb = (unsigned short*)(ws + OFF_XB);
  unsigned short* Lg = (unsigned short*)(ws + OFF_LG);
  float* q = (float*)(ws + OFF_Q);
  int* cidx = (int*)(ws + OFF_CIDX);
  int* ccnt = (int*)(ws + OFF_CCNT);
  int* coarse = (int*)(ws + OFF_COARSE);

  k_transpose<<<65536, 256, 0, stream>>>(Wr, WT, WTb);
  k_cvt_x<<<4096, 256, 0, stream>>>(x, xb);
  k_gemm<<<16384, 256, 0, stream>>>(xb, WTb, Lg);
  k_select<<<4096, 256, 0, stream>>>(Lg, cidx, ccnt);
  k_rescore<<<4096, 256, 0, stream>>>(x, WT, cidx, ccnt, coarse);
  k_query<<<1024, 128, 0, stream>>>(x, Wenc, q);
  k_fine<<<4096, 256, 0, stream>>>(q, Kall, Vall, coarse, out);
}